// Round 1
// baseline (1541.302 us; speedup 1.0000x reference)
//
#include <hip/hip_runtime.h>
#include <hip/hip_bf16.h>

// BinaryTreeLSTM  B=64, L=1024, IN_DIM=300, MEM=256
//
// Plan:
//  1. pack_leaf_k:  Wco packed as (320,512) [k][j], j=o*2+{c,o-gate}, K zero-padded 300->320
//  2. pack_level_k: W2 packed as (512,1024) [k][j], j=o*4+gate, k<256 -> Wl, k>=256 -> Wr
//  3. leaf_gemm:    (65536x300)@(300x512) fused sigmoid/tanh -> c0,h0 (65536,256)
//  4. level_gemm x10: X=(h viewed as (M,512)) @ (512x1024), fused gates -> c,h (M,256)
//     Level input gather is FREE: h(B,n,256) rows [2p,2p+1] are contiguous 512 floats.
//  Last level writes directly to d_out: [c(64,256), h(64,256)].

__device__ __forceinline__ float fsig(float x)  { return 1.f / (1.f + __expf(-x)); }
__device__ __forceinline__ float ftanh(float x) { return 1.f - 2.f / (__expf(2.f * x) + 1.f); }

// ---------------- pack kernels ----------------

__global__ void pack_leaf_k(const float* __restrict__ Wcx, const float* __restrict__ Wox,
                            const float* __restrict__ bcx, const float* __restrict__ box,
                            float* __restrict__ Wp, float* __restrict__ bp)
{
    int idx = blockIdx.x * 256 + threadIdx.x;   // over 320*512
    if (idx < 320 * 512) {
        int k = idx >> 9;          // row (padded K)
        int j = idx & 511;         // col: o*2 + g
        int o = j >> 1, g = j & 1;
        float v = 0.f;
        if (k < 300) v = g ? Wox[o * 300 + k] : Wcx[o * 300 + k];
        Wp[idx] = v;
    }
    if (idx < 512) {
        int o = idx >> 1, g = idx & 1;
        bp[idx] = g ? box[o] : bcx[o];
    }
}

__global__ void pack_level_k(const float* __restrict__ Wl, const float* __restrict__ Wr,
                             const float* __restrict__ bl, const float* __restrict__ br,
                             float* __restrict__ Wp, float* __restrict__ bp)
{
    int idx = blockIdx.x * 256 + threadIdx.x;   // over 512*1024
    if (idx < 512 * 1024) {
        int k = idx >> 10;
        int j = idx & 1023;        // col: o*4 + g
        int o = j >> 2, g = j & 3;
        float v = (k < 256) ? Wl[(g * 256 + o) * 256 + k]
                            : Wr[(g * 256 + o) * 256 + (k - 256)];
        Wp[idx] = v;
    }
    if (idx < 1024) {
        int o = idx >> 2, g = idx & 3;
        bp[idx] = bl[g * 256 + o] + br[g * 256 + o];
    }
}

// ---------------- leaf GEMM (fused) ----------------
// A (65536,300) * Wp(320,512 [k][j]) -> c,h (65536,256)
// BM=64, BN=256, BK=16, 256 threads, thread tile 4 rows x 16 cols.

__global__ __launch_bounds__(256, 2)
void leaf_gemm(const float* __restrict__ A,
               const float* __restrict__ Wp,
               const float* __restrict__ bp,
               float* __restrict__ c_out, float* __restrict__ h_out)
{
    __shared__ float As[16][64];     // [k][row]
    __shared__ float Ws[16][256];    // [k][col]

    const int rowBlk = blockIdx.x * 64;
    const int colBlk = blockIdx.y * 256;      // 0 or 256
    const int tid = threadIdx.x;
    const int ty = tid >> 4, tx = tid & 15;

    float acc[4][16];
#pragma unroll
    for (int r = 0; r < 4; ++r)
#pragma unroll
        for (int i = 0; i < 16; ++i) acc[r][i] = 0.f;

    const int ar  = tid & 63;   // A row in tile
    const int akq = tid >> 6;   // 0..3 -> k group
    const int wk  = tid >> 4;   // Ws row 0..15
    const int wtl = tid & 15;

    const float* arow = A + (size_t)(rowBlk + ar) * 300;

    for (int kc = 0; kc < 320; kc += 16) {
        // stage A (transpose, zero-pad K>=300)
#pragma unroll
        for (int j = 0; j < 4; ++j) {
            int kk = kc + akq * 4 + j;
            As[akq * 4 + j][ar] = (kk < 300) ? arow[kk] : 0.f;
        }
        // stage W: row kc+wk, 4 float4s
#pragma unroll
        for (int q = 0; q < 4; ++q) {
            const float4 w = *(const float4*)(Wp + (size_t)(kc + wk) * 512 + colBlk + wtl * 4 + 64 * q);
            *(float4*)&Ws[wk][wtl * 4 + 64 * q] = w;
        }
        __syncthreads();
#pragma unroll
        for (int k = 0; k < 16; ++k) {
            float4 a4 = *(const float4*)&As[k][ty * 4];
            float av[4] = {a4.x, a4.y, a4.z, a4.w};
#pragma unroll
            for (int q = 0; q < 4; ++q) {
                float4 w4 = *(const float4*)&Ws[k][tx * 4 + 64 * q];
                float wv[4] = {w4.x, w4.y, w4.z, w4.w};
#pragma unroll
                for (int r = 0; r < 4; ++r)
#pragma unroll
                    for (int ii = 0; ii < 4; ++ii)
                        acc[r][q * 4 + ii] = fmaf(av[r], wv[ii], acc[r][q * 4 + ii]);
            }
        }
        __syncthreads();
    }

    // epilogue: j = o*2+g  ->  float4 = [c(o0), o(o0), c(o0+1), o(o0+1)]
#pragma unroll
    for (int q = 0; q < 4; ++q) {
        int jb = colBlk + q * 64 + tx * 4;
        int o0 = jb >> 1;
        float bc0 = bp[jb], bo0 = bp[jb + 1], bc1 = bp[jb + 2], bo1 = bp[jb + 3];
#pragma unroll
        for (int r = 0; r < 4; ++r) {
            int row = rowBlk + ty * 4 + r;
            float cv0 = acc[r][q * 4 + 0] + bc0;
            float ov0 = acc[r][q * 4 + 1] + bo0;
            float cv1 = acc[r][q * 4 + 2] + bc1;
            float ov1 = acc[r][q * 4 + 3] + bo1;
            c_out[(size_t)row * 256 + o0]     = cv0;
            h_out[(size_t)row * 256 + o0]     = fsig(ov0) * ftanh(cv0);
            c_out[(size_t)row * 256 + o0 + 1] = cv1;
            h_out[(size_t)row * 256 + o0 + 1] = fsig(ov1) * ftanh(cv1);
        }
    }
}

// ---------------- level GEMM (fused gates) ----------------
// Hprev viewed as (M,512) contiguous; G = Hprev @ Wp(512,1024) ; fused LSTM node update.

__global__ __launch_bounds__(256, 2)
void level_gemm(const float* __restrict__ Hprev,   // (M,512)
                const float* __restrict__ Cprev,   // (M,512)
                const float* __restrict__ Wp,      // (512,1024) [k][j]
                const float* __restrict__ bp,      // (1024)
                float* __restrict__ c_out, float* __restrict__ h_out) // (M,256)
{
    __shared__ float As[16][64];
    __shared__ float Ws[16][256];

    const int rowBlk = blockIdx.x * 64;
    const int colBlk = blockIdx.y * 256;
    const int tid = threadIdx.x;
    const int ty = tid >> 4, tx = tid & 15;

    float acc[4][16];
#pragma unroll
    for (int r = 0; r < 4; ++r)
#pragma unroll
        for (int i = 0; i < 16; ++i) acc[r][i] = 0.f;

    const int ar  = tid & 63;
    const int akq = tid >> 6;
    const int wk  = tid >> 4;
    const int wtl = tid & 15;

    for (int kc = 0; kc < 512; kc += 16) {
        float4 a4 = *(const float4*)(Hprev + (size_t)(rowBlk + ar) * 512 + kc + akq * 4);
        As[akq * 4 + 0][ar] = a4.x;
        As[akq * 4 + 1][ar] = a4.y;
        As[akq * 4 + 2][ar] = a4.z;
        As[akq * 4 + 3][ar] = a4.w;
#pragma unroll
        for (int q = 0; q < 4; ++q) {
            const float4 w = *(const float4*)(Wp + (size_t)(kc + wk) * 1024 + colBlk + wtl * 4 + 64 * q);
            *(float4*)&Ws[wk][wtl * 4 + 64 * q] = w;
        }
        __syncthreads();
#pragma unroll
        for (int k = 0; k < 16; ++k) {
            float4 av4 = *(const float4*)&As[k][ty * 4];
            float av[4] = {av4.x, av4.y, av4.z, av4.w};
#pragma unroll
            for (int q = 0; q < 4; ++q) {
                float4 w4 = *(const float4*)&Ws[k][tx * 4 + 64 * q];
                float wv[4] = {w4.x, w4.y, w4.z, w4.w};
#pragma unroll
                for (int r = 0; r < 4; ++r)
#pragma unroll
                    for (int ii = 0; ii < 4; ++ii)
                        acc[r][q * 4 + ii] = fmaf(av[r], wv[ii], acc[r][q * 4 + ii]);
            }
        }
        __syncthreads();
    }

    // epilogue: j = o*4+g -> float4 = [i, lf, rf, u] for one o
#pragma unroll
    for (int q = 0; q < 4; ++q) {
        int jb = colBlk + q * 64 + tx * 4;
        int o = jb >> 2;
        float b0 = bp[jb], b1 = bp[jb + 1], b2 = bp[jb + 2], b3 = bp[jb + 3];
#pragma unroll
        for (int r = 0; r < 4; ++r) {
            int row = rowBlk + ty * 4 + r;
            float gi = fsig(acc[r][q * 4 + 0] + b0);
            float lf = fsig(acc[r][q * 4 + 1] + b1);
            float rf = fsig(acc[r][q * 4 + 2] + b2);
            float gu = ftanh(acc[r][q * 4 + 3] + b3);
            float lc = Cprev[(size_t)row * 512 + o];
            float rc = Cprev[(size_t)row * 512 + 256 + o];
            float cv = gi * gu + lf * lc + rf * rc;
            c_out[(size_t)row * 256 + o] = cv;
            h_out[(size_t)row * 256 + o] = ftanh(cv);
        }
    }
}

// ---------------- host ----------------

extern "C" void kernel_launch(void* const* d_in, const int* in_sizes, int n_in,
                              void* d_out, int out_size, void* d_ws, size_t ws_size,
                              hipStream_t stream)
{
    const float* embs = (const float*)d_in[0];
    const float* Wcx  = (const float*)d_in[1];
    const float* bcx  = (const float*)d_in[2];
    const float* Wox  = (const float*)d_in[3];
    const float* box  = (const float*)d_in[4];
    const float* Wl   = (const float*)d_in[5];
    const float* bl   = (const float*)d_in[6];
    const float* Wr   = (const float*)d_in[7];
    const float* br   = (const float*)d_in[8];

    float* ws = (float*)d_ws;
    float* WpL = ws;  ws += 320 * 512;
    float* bpL = ws;  ws += 512;
    float* Wp2 = ws;  ws += 512 * 1024;
    float* bp2 = ws;  ws += 1024;
    float* c0  = ws;  ws += 64 * 1024 * 256;   // leaf c (also reused as ping-pong B)
    float* h0  = ws;  ws += 64 * 1024 * 256;
    float* cA  = ws;  ws += 64 * 512 * 256;
    float* hA  = ws;  ws += 64 * 512 * 256;

    pack_leaf_k<<<(320 * 512 + 255) / 256, 256, 0, stream>>>(Wcx, Wox, bcx, box, WpL, bpL);
    pack_level_k<<<(512 * 1024 + 255) / 256, 256, 0, stream>>>(Wl, Wr, bl, br, Wp2, bp2);

    leaf_gemm<<<dim3(1024, 2), 256, 0, stream>>>(embs, WpL, bpL, c0, h0);

    float* cin = c0; float* hin = h0;
    float* cping[2] = {cA, c0};
    float* hping[2] = {hA, h0};
    int flip = 0;
    for (int np = 512; np >= 1; np >>= 1) {
        float* co; float* ho;
        if (np == 1) { co = (float*)d_out; ho = (float*)d_out + 64 * 256; }
        else         { co = cping[flip];  ho = hping[flip]; }
        level_gemm<<<dim3(np, 4), 256, 0, stream>>>(hin, cin, Wp2, bp2, co, ho);
        cin = co; hin = ho;
        flip ^= 1;
    }
}

// Round 2
// 283.693 us; speedup vs baseline: 5.4330x; 5.4330x over previous
//
#include <hip/hip_runtime.h>
#include <hip/hip_bf16.h>

// BinaryTreeLSTM  B=64, L=1024, IN_DIM=300, MEM=256 — bf16 MFMA version.
//
// Layouts:
//  - gates de-interleaved: col j = g*256 + o  (leaf: g in {c,o}, levels: {i,lf,rf,u})
//  - weights packed in MFMA fragment order: 16B chunk at
//      Wb[((t*NG + g)*256 + o)*4 + slot],  slot = q ^ (o&3),
//    holding B[k = t*32 + q*8 + e][g*256+o], e=0..7  (bf16)
//    -> global_load_lds stages 4KB/gate/K-step LINEARLY into LDS, and
//       ds_read_b128 fragment reads are bank-balanced (XOR swizzle).
//  - A (embs_bf16 / h) row-major (M,K) bf16; staged with same slot swizzle.
//  - c carried fp32; h carried bf16 (GEMM input).

typedef __attribute__((ext_vector_type(8))) short bf16x8;
typedef __attribute__((ext_vector_type(4))) float f32x4;

__device__ __forceinline__ float fsig(float x)  { return 1.f / (1.f + __expf(-x)); }
__device__ __forceinline__ float ftanh(float x) { return 1.f - 2.f / (__expf(2.f * x) + 1.f); }
__device__ __forceinline__ ushort f2bf(float x) {
    __hip_bfloat16 b = __float2bfloat16(x);
    return *reinterpret_cast<ushort*>(&b);
}

__device__ __forceinline__ void gld_lds16(const void* g, void* l) {
    __builtin_amdgcn_global_load_lds((const __attribute__((address_space(1))) void*)g,
                                     (__attribute__((address_space(3))) void*)l, 16, 0, 0);
}

// ---------------- embs fp32 -> bf16 (pad K 300->320) ----------------
__global__ void conv_embs(const float* __restrict__ E, ushort* __restrict__ Eb)
{
    int tid = blockIdx.x * 256 + threadIdx.x;       // 65536*80 threads
    int row = tid / 80;
    int k = (tid - row * 80) * 4;
    float4 v = make_float4(0.f, 0.f, 0.f, 0.f);
    if (k < 300) v = *(const float4*)(E + (size_t)row * 300 + k);
    ushort4 o;
    o.x = f2bf(v.x); o.y = f2bf(v.y); o.z = f2bf(v.z); o.w = f2bf(v.w);
    *(ushort4*)(Eb + (size_t)row * 320 + k) = o;
}

// ---------------- weight pack kernels ----------------
// leaf: NG=2, NT=10 (K 300 padded to 320). elems = 10*2*256*4*8 = 163840
__global__ void pack_leaf_k(const float* __restrict__ Wcx, const float* __restrict__ Wox,
                            const float* __restrict__ bcx, const float* __restrict__ box,
                            ushort* __restrict__ Wb, float* __restrict__ bp)
{
    int idx = blockIdx.x * 256 + threadIdx.x;
    if (idx < 163840) {
        int e = idx & 7, slot = (idx >> 3) & 3, o = (idx >> 5) & 255;
        int g = (idx >> 13) & 1, t = idx >> 14;
        int q = slot ^ (o & 3);
        int k = t * 32 + q * 8 + e;
        float v = 0.f;
        if (k < 300) v = g ? Wox[o * 300 + k] : Wcx[o * 300 + k];
        Wb[idx] = f2bf(v);
    }
    if (idx < 512) {
        int g = idx >> 8, o = idx & 255;
        bp[idx] = g ? box[o] : bcx[o];
    }
}

// level: NG=4, NT=16 (K=512). elems = 16*4*256*4*8 = 524288
__global__ void pack_level_k(const float* __restrict__ Wl, const float* __restrict__ Wr,
                             const float* __restrict__ bl, const float* __restrict__ br,
                             ushort* __restrict__ Wb, float* __restrict__ bp)
{
    int idx = blockIdx.x * 256 + threadIdx.x;
    if (idx < 524288) {
        int e = idx & 7, slot = (idx >> 3) & 3, o = (idx >> 5) & 255;
        int g = (idx >> 13) & 3, t = idx >> 15;
        int q = slot ^ (o & 3);
        int k = t * 32 + q * 8 + e;
        float v = (k < 256) ? Wl[(g * 256 + o) * 256 + k]
                            : Wr[(g * 256 + o) * 256 + (k - 256)];
        Wb[idx] = f2bf(v);
    }
    if (idx < 1024) bp[idx] = bl[idx] + br[idx];
}

// ---------------- fused MFMA GEMM ----------------
// Block: 64 rows x 64 o-cols x NG gates. 4 waves (2x2), wave tile 32x32.
// MODE 0 = leaf (NG=2), 1 = level (NG=4, h->bf16), 2 = last level (h->fp32)

template<int NG, int NT, int MODE>
__global__ __launch_bounds__(256, 2)
void mfma_gemm(const ushort* __restrict__ A,     // (M, NT*32) bf16
               const ushort* __restrict__ Wb,    // packed weights
               const float* __restrict__ bp,     // (NG*256)
               const float* __restrict__ Cprev,  // (M, 512) fp32, levels only
               float* __restrict__ c_out,        // (M, 256) fp32
               ushort* __restrict__ h_out,       // (M, 256) bf16 (MODE 0/1)
               float* __restrict__ hf_out)       // (M, 256) fp32 (MODE 2)
{
    constexpr int K = NT * 32;
    __shared__ __align__(16) ushort As[2][2048];       // 64 rows * 32 k
    __shared__ __align__(16) ushort Bs[2][NG * 2048];  // NG * 64 cols * 32 k

    const int tid = threadIdx.x;
    const int wid = tid >> 6, ln = tid & 63;
    const int lq = ln >> 4, lr = ln & 15;
    const int wm = wid >> 1, wn = wid & 1;
    const int rowBlk = blockIdx.x * 64;
    const int o0 = blockIdx.y * 64;

    f32x4 acc[2][2][NG];
#pragma unroll
    for (int m = 0; m < 2; ++m)
#pragma unroll
        for (int n = 0; n < 2; ++n)
#pragma unroll
            for (int g = 0; g < NG; ++g) acc[m][n][g] = f32x4{0.f, 0.f, 0.f, 0.f};

    const int srow = wid * 16 + (ln >> 2);            // staging row for this lane
    const int sq   = (ln & 3) ^ ((ln >> 2) & 3);      // staging k-quarter (slot-swizzled)
    const ushort* aRow = A + (size_t)(rowBlk + srow) * K + sq * 8;

    // prologue: stage t=0 into buf 0
    gld_lds16(aRow, &As[0][wid * 512]);
#pragma unroll
    for (int s = 0; s < NG; ++s)
        gld_lds16(Wb + ((size_t)s * 1024 + (o0 << 2) + wid * 64 + ln) * 8,
                  &Bs[0][(s * 256 + wid * 64) * 8]);

    for (int t = 0; t < NT; ++t) {
        __syncthreads();            // drains vmcnt -> buf[cur] staged; orders buffer reuse
        const int cur = t & 1;
        if (t + 1 < NT) {
            gld_lds16(aRow + (t + 1) * 32, &As[cur ^ 1][wid * 512]);
#pragma unroll
            for (int s = 0; s < NG; ++s)
                gld_lds16(Wb + ((size_t)((t + 1) * NG + s) * 1024 + (o0 << 2) + wid * 64 + ln) * 8,
                          &Bs[cur ^ 1][(s * 256 + wid * 64) * 8]);
        }
        bf16x8 a[2];
#pragma unroll
        for (int m = 0; m < 2; ++m) {
            int rL = wm * 32 + m * 16 + lr;
            a[m] = *(const bf16x8*)&As[cur][(rL * 4 + (lq ^ (lr & 3))) * 8];
        }
#pragma unroll
        for (int n = 0; n < 2; ++n) {
            int cL = wn * 32 + n * 16 + lr;
#pragma unroll
            for (int g = 0; g < NG; ++g) {
                bf16x8 b = *(const bf16x8*)&Bs[cur][((g * 64 + cL) * 4 + (lq ^ (lr & 3))) * 8];
#pragma unroll
                for (int m = 0; m < 2; ++m)
                    acc[m][n][g] = __builtin_amdgcn_mfma_f32_16x16x32_bf16(a[m], b, acc[m][n][g], 0, 0, 0);
            }
        }
    }

    // epilogue: D row = 4*lq + j (within 16), col = lr (within 16)
#pragma unroll
    for (int m = 0; m < 2; ++m)
#pragma unroll
    for (int n = 0; n < 2; ++n) {
        const int row0 = rowBlk + wm * 32 + m * 16 + lq * 4;
        const int col  = o0 + wn * 32 + n * 16 + lr;
        if constexpr (MODE == 0) {
            const float bc = bp[col], bo = bp[256 + col];
#pragma unroll
            for (int j = 0; j < 4; ++j) {
                int row = row0 + j;
                float cv = acc[m][n][0][j] + bc;
                float ov = acc[m][n][1][j] + bo;
                c_out[(size_t)row * 256 + col] = cv;
                h_out[(size_t)row * 256 + col] = f2bf(fsig(ov) * ftanh(cv));
            }
        } else {
            const float bi  = bp[col],       blf = bp[256 + col];
            const float brf = bp[512 + col], bu  = bp[768 + col];
#pragma unroll
            for (int j = 0; j < 4; ++j) {
                int row = row0 + j;
                float gi = fsig(acc[m][n][0][j] + bi);
                float lf = fsig(acc[m][n][1][j] + blf);
                float rf = fsig(acc[m][n][2][j] + brf);
                float gu = ftanh(acc[m][n][3][j] + bu);
                float lc = Cprev[(size_t)row * 512 + col];
                float rc = Cprev[(size_t)row * 512 + 256 + col];
                float cv = gi * gu + lf * lc + rf * rc;
                float hv = ftanh(cv);
                c_out[(size_t)row * 256 + col] = cv;
                if constexpr (MODE == 2) hf_out[(size_t)row * 256 + col] = hv;
                else                     h_out[(size_t)row * 256 + col] = f2bf(hv);
            }
        }
    }
}

// ---------------- host ----------------

extern "C" void kernel_launch(void* const* d_in, const int* in_sizes, int n_in,
                              void* d_out, int out_size, void* d_ws, size_t ws_size,
                              hipStream_t stream)
{
    const float* embs = (const float*)d_in[0];
    const float* Wcx  = (const float*)d_in[1];
    const float* bcx  = (const float*)d_in[2];
    const float* Wox  = (const float*)d_in[3];
    const float* box  = (const float*)d_in[4];
    const float* Wl   = (const float*)d_in[5];
    const float* bl   = (const float*)d_in[6];
    const float* Wr   = (const float*)d_in[7];
    const float* br   = (const float*)d_in[8];

    char* p = (char*)d_ws;
    ushort* Wb2 = (ushort*)p;  p += (size_t)524288 * 2;
    ushort* WbL = (ushort*)p;  p += (size_t)163840 * 2;
    float*  bp2 = (float*)p;   p += 1024 * 4;
    float*  bpL = (float*)p;   p += 512 * 4;
    float*  c0  = (float*)p;   p += (size_t)65536 * 256 * 4;   // 64 MB
    ushort* h0  = (ushort*)p;  p += (size_t)65536 * 256 * 2;   // 32 MB
    char* X = p;
    ushort* embsB = (ushort*)X;                                 // 40 MB (dead after leaf)
    float*  cA = (float*)X;                                     // 32 MB
    ushort* hA = (ushort*)(X + (size_t)32768 * 256 * 4);        // 16 MB
    float*  cB = (float*)(X + (size_t)48 * 1024 * 1024);        // 16 MB
    ushort* hB = (ushort*)(X + (size_t)64 * 1024 * 1024);       // 8 MB

    conv_embs<<<20480, 256, 0, stream>>>(embs, embsB);
    pack_leaf_k<<<640, 256, 0, stream>>>(Wcx, Wox, bcx, box, WbL, bpL);
    pack_level_k<<<2048, 256, 0, stream>>>(Wl, Wr, bl, br, Wb2, bp2);

    // leaf: (65536,320) @ (320, 2*256) fused -> c0 fp32, h0 bf16
    mfma_gemm<2, 10, 0><<<dim3(1024, 4), 256, 0, stream>>>(
        embsB, WbL, bpL, nullptr, c0, h0, nullptr);

    const ushort* hin = h0;
    const float*  cin = c0;
    float*  cping[2] = {cA, cB};
    ushort* hping[2] = {hA, hB};
    int flip = 0;
    for (int np = 512; np >= 1; np >>= 1) {
        int M = 64 * np;
        if (np == 1) {
            mfma_gemm<4, 16, 2><<<dim3(1, 4), 256, 0, stream>>>(
                hin, Wb2, bp2, cin, (float*)d_out, nullptr, (float*)d_out + 64 * 256);
        } else {
            float* co = cping[flip]; ushort* ho = hping[flip];
            mfma_gemm<4, 16, 1><<<dim3(M / 64, 4), 256, 0, stream>>>(
                hin, Wb2, bp2, cin, co, ho, nullptr);
            cin = co; hin = ho; flip ^= 1;
        }
    }
}